// Round 2
// baseline (2901.885 us; speedup 1.0000x reference)
//
#include <hip/hip_runtime.h>
#include <hip/hip_bf16.h>
#include <math.h>

#define N_TOK 8192
#define DIM   1024
#define HID   2048
#define NE    8
#define TOPK  2

#define BM 64
#define BN 64
#define BK 32

// ---------------- gating: logits -> softmax -> top2 -> routing lists ----------------
__global__ __launch_bounds__(256) void gate_kernel(
    const float* __restrict__ x, const float* __restrict__ gw, const float* __restrict__ gb,
    float* __restrict__ usage, int* __restrict__ counts,
    int* __restrict__ lists, float* __restrict__ wts)
{
    const int wave_in_block = threadIdx.x >> 6;
    const int lane = threadIdx.x & 63;
    const int tok = blockIdx.x * 4 + wave_in_block;   // 4 waves/block

    __shared__ float su[NE];
    if (threadIdx.x < NE) su[threadIdx.x] = 0.f;
    __syncthreads();

    float acc[NE];
#pragma unroll
    for (int e = 0; e < NE; e++) acc[e] = 0.f;

    const float* xr = x + (size_t)tok * DIM;
    for (int d = lane; d < DIM; d += 64) {
        float xv = xr[d];
        const float4* g4 = (const float4*)(gw + (size_t)d * NE);
        float4 ga = g4[0], gc = g4[1];
        acc[0] = fmaf(xv, ga.x, acc[0]);
        acc[1] = fmaf(xv, ga.y, acc[1]);
        acc[2] = fmaf(xv, ga.z, acc[2]);
        acc[3] = fmaf(xv, ga.w, acc[3]);
        acc[4] = fmaf(xv, gc.x, acc[4]);
        acc[5] = fmaf(xv, gc.y, acc[5]);
        acc[6] = fmaf(xv, gc.z, acc[6]);
        acc[7] = fmaf(xv, gc.w, acc[7]);
    }
#pragma unroll
    for (int e = 0; e < NE; e++) {
#pragma unroll
        for (int off = 32; off > 0; off >>= 1)
            acc[e] += __shfl_xor(acc[e], off);
    }

    if (lane == 0) {
        float lg[NE], p[NE];
        float mx = -1e30f;
#pragma unroll
        for (int e = 0; e < NE; e++) { lg[e] = acc[e] + gb[e]; mx = fmaxf(mx, lg[e]); }
        float s = 0.f;
#pragma unroll
        for (int e = 0; e < NE; e++) { p[e] = __expf(lg[e] - mx); s += p[e]; }
        float inv = 1.f / s;
#pragma unroll
        for (int e = 0; e < NE; e++) p[e] *= inv;

        // per-block usage partial
#pragma unroll
        for (int e = 0; e < NE; e++) atomicAdd(&su[e], p[e]);

        // top-2 (ties -> lowest index, matches lax.top_k)
        int e1 = 0; float v1 = p[0];
#pragma unroll
        for (int e = 1; e < NE; e++) if (p[e] > v1) { v1 = p[e]; e1 = e; }
        int e2 = -1; float v2 = -1e30f;
#pragma unroll
        for (int e = 0; e < NE; e++) if (e != e1 && p[e] > v2) { v2 = p[e]; e2 = e; }

        int pos1 = atomicAdd(&counts[e1], 1);
        lists[e1 * N_TOK + pos1] = tok * 2 + 0;
        wts[e1 * N_TOK + pos1] = v1;
        int pos2 = atomicAdd(&counts[e2], 1);
        lists[e2 * N_TOK + pos2] = tok * 2 + 1;
        wts[e2 * N_TOK + pos2] = v2;
    }
    __syncthreads();
    if (threadIdx.x < NE) atomicAdd(&usage[threadIdx.x], su[threadIdx.x]);
}

__global__ void loss_kernel(const float* __restrict__ usage, float* __restrict__ out_loss)
{
    if (threadIdx.x == 0) {
        float l = 0.f;
        for (int e = 0; e < NE; e++) {
            float u = usage[e] / (float)N_TOK;
            l += u * logf(u + 1e-9f);
        }
        *out_loss = l;
    }
}

// ---------------- pass A: Xg @ {w1,w2} + bias -> swiglu -> H ----------------
__global__ __launch_bounds__(256) void ffn1_kernel(
    const float* __restrict__ x,
    const float* __restrict__ w1, const float* __restrict__ b1,
    const float* __restrict__ w2, const float* __restrict__ b2,
    const int* __restrict__ counts, const int* __restrict__ lists,
    float* __restrict__ Hbuf)
{
    const int e = blockIdx.z;
    const int tileM = blockIdx.y;
    const int n0 = blockIdx.x * BN;
    const int cnt = counts[e];
    if (tileM * BM >= cnt) return;

    __shared__ float Xs[BK][BM + 4];   // transposed [k][m], stride 68 keeps float4 alignment
    __shared__ float W1s[BK][BN];
    __shared__ float W2s[BK][BN];
    __shared__ int rowids[BM];

    const int tid = threadIdx.x;
    if (tid < BM) {
        int idx = tileM * BM + tid;
        rowids[tid] = (idx < cnt) ? lists[e * N_TOK + idx] : -1;
    }
    __syncthreads();

    const float* W1p = w1 + (size_t)e * DIM * HID;
    const float* W2p = w2 + (size_t)e * DIM * HID;

    float acc1[4][4] = {{0.f}}, acc2[4][4] = {{0.f}};
    const int ty = tid >> 4, tx = tid & 15;

    for (int k0 = 0; k0 < DIM; k0 += BK) {
        // stage X tile (gathered rows), store transposed
#pragma unroll
        for (int i = 0; i < 2; i++) {
            int s = tid + i * 256;                  // 0..511
            int m = s >> 3, c4 = (s & 7) * 4;
            int rid = rowids[m];
            float4 v = make_float4(0.f, 0.f, 0.f, 0.f);
            if (rid >= 0) {
                int t = rid >> 1;
                v = *(const float4*)(x + (size_t)t * DIM + k0 + c4);
            }
            Xs[c4 + 0][m] = v.x; Xs[c4 + 1][m] = v.y;
            Xs[c4 + 2][m] = v.z; Xs[c4 + 3][m] = v.w;
        }
        // stage W1/W2 tiles
#pragma unroll
        for (int i = 0; i < 2; i++) {
            int s = tid + i * 256;
            int kr = s >> 4, c4 = (s & 15) * 4;
            *(float4*)&W1s[kr][c4] = *(const float4*)(W1p + (size_t)(k0 + kr) * HID + n0 + c4);
            *(float4*)&W2s[kr][c4] = *(const float4*)(W2p + (size_t)(k0 + kr) * HID + n0 + c4);
        }
        __syncthreads();
#pragma unroll
        for (int kk = 0; kk < BK; kk++) {
            float4 a  = *(const float4*)&Xs[kk][ty * 4];
            float4 bA = *(const float4*)&W1s[kk][tx * 4];
            float4 bB = *(const float4*)&W2s[kk][tx * 4];
            float av[4]  = {a.x, a.y, a.z, a.w};
            float bAv[4] = {bA.x, bA.y, bA.z, bA.w};
            float bBv[4] = {bB.x, bB.y, bB.z, bB.w};
#pragma unroll
            for (int r = 0; r < 4; r++)
#pragma unroll
                for (int c = 0; c < 4; c++) {
                    acc1[r][c] = fmaf(av[r], bAv[c], acc1[r][c]);
                    acc2[r][c] = fmaf(av[r], bBv[c], acc2[r][c]);
                }
        }
        __syncthreads();
    }

    // epilogue: bias + swiglu, write H rows
#pragma unroll
    for (int r = 0; r < 4; r++) {
        int m = ty * 4 + r;
        int rid = rowids[m];
        if (rid < 0) continue;
        float o[4];
#pragma unroll
        for (int c = 0; c < 4; c++) {
            int col = n0 + tx * 4 + c;
            float v1 = acc1[r][c] + b1[e * HID + col];
            float v2 = acc2[r][c] + b2[e * HID + col];
            float g = 1.f / (1.f + __expf(-v2));
            o[c] = v1 * g;
        }
        *(float4*)(Hbuf + (size_t)rid * HID + n0 + tx * 4) = make_float4(o[0], o[1], o[2], o[3]);
    }
}

// ---------------- pass B: Hg @ w3 + b3, scale by combine weight, atomic add into out ----------------
__global__ __launch_bounds__(256) void ffn2_kernel(
    const float* __restrict__ Hbuf,
    const float* __restrict__ w3, const float* __restrict__ b3,
    const int* __restrict__ counts, const int* __restrict__ lists, const float* __restrict__ wts,
    float* __restrict__ out)
{
    const int e = blockIdx.z;
    const int tileM = blockIdx.y;
    const int n0 = blockIdx.x * BN;
    const int cnt = counts[e];
    if (tileM * BM >= cnt) return;

    __shared__ float Hs[BK][BM + 4];
    __shared__ float W3s[BK][BN];
    __shared__ int rowids[BM];
    __shared__ float rowwt[BM];

    const int tid = threadIdx.x;
    if (tid < BM) {
        int idx = tileM * BM + tid;
        if (idx < cnt) { rowids[tid] = lists[e * N_TOK + idx]; rowwt[tid] = wts[e * N_TOK + idx]; }
        else           { rowids[tid] = -1; rowwt[tid] = 0.f; }
    }
    __syncthreads();

    const float* W3p = w3 + (size_t)e * HID * DIM;
    float acc[4][4] = {{0.f}};
    const int ty = tid >> 4, tx = tid & 15;

    for (int k0 = 0; k0 < HID; k0 += BK) {
#pragma unroll
        for (int i = 0; i < 2; i++) {
            int s = tid + i * 256;
            int m = s >> 3, c4 = (s & 7) * 4;
            int rid = rowids[m];
            float4 v = make_float4(0.f, 0.f, 0.f, 0.f);
            if (rid >= 0)
                v = *(const float4*)(Hbuf + (size_t)rid * HID + k0 + c4);
            Hs[c4 + 0][m] = v.x; Hs[c4 + 1][m] = v.y;
            Hs[c4 + 2][m] = v.z; Hs[c4 + 3][m] = v.w;
        }
#pragma unroll
        for (int i = 0; i < 2; i++) {
            int s = tid + i * 256;
            int kr = s >> 4, c4 = (s & 15) * 4;
            *(float4*)&W3s[kr][c4] = *(const float4*)(W3p + (size_t)(k0 + kr) * DIM + n0 + c4);
        }
        __syncthreads();
#pragma unroll
        for (int kk = 0; kk < BK; kk++) {
            float4 a = *(const float4*)&Hs[kk][ty * 4];
            float4 b = *(const float4*)&W3s[kk][tx * 4];
            float av[4] = {a.x, a.y, a.z, a.w};
            float bv[4] = {b.x, b.y, b.z, b.w};
#pragma unroll
            for (int r = 0; r < 4; r++)
#pragma unroll
                for (int c = 0; c < 4; c++)
                    acc[r][c] = fmaf(av[r], bv[c], acc[r][c]);
        }
        __syncthreads();
    }

#pragma unroll
    for (int r = 0; r < 4; r++) {
        int m = ty * 4 + r;
        int rid = rowids[m];
        if (rid < 0) continue;
        int t = rid >> 1;
        float w = rowwt[m];
        float* orow = out + (size_t)t * DIM + n0 + tx * 4;
#pragma unroll
        for (int c = 0; c < 4; c++) {
            int col = n0 + tx * 4 + c;
            float v = (acc[r][c] + b3[e * DIM + col]) * w;
            atomicAdd(&orow[c], v);
        }
    }
}

extern "C" void kernel_launch(void* const* d_in, const int* in_sizes, int n_in,
                              void* d_out, int out_size, void* d_ws, size_t ws_size,
                              hipStream_t stream) {
    const float* x      = (const float*)d_in[0];
    const float* gate_w = (const float*)d_in[1];
    const float* gate_b = (const float*)d_in[2];
    const float* w1     = (const float*)d_in[3];
    const float* b1     = (const float*)d_in[4];
    const float* w2     = (const float*)d_in[5];
    const float* b2     = (const float*)d_in[6];
    const float* w3     = (const float*)d_in[7];
    const float* b3     = (const float*)d_in[8];
    float* out = (float*)d_out;

    // workspace layout
    char* ws = (char*)d_ws;
    float* usage = (float*)ws;                                   // 8 f32
    int*   counts = (int*)(ws + 32);                             // 8 i32
    int*   lists  = (int*)(ws + 64);                             // E*N i32
    float* wts    = (float*)(ws + 64 + (size_t)NE * N_TOK * 4);  // E*N f32
    float* Hbuf   = (float*)(ws + 64 + (size_t)2 * NE * N_TOK * 4); // N*K*HID f32 (134MB)

    hipMemsetAsync(ws, 0, 64, stream);
    hipMemsetAsync(d_out, 0, (size_t)N_TOK * DIM * sizeof(float), stream);

    gate_kernel<<<N_TOK / 4, 256, 0, stream>>>(x, gate_w, gate_b, usage, counts, lists, wts);
    loss_kernel<<<1, 64, 0, stream>>>(usage, out + (size_t)N_TOK * DIM);

    dim3 gA(HID / BN, N_TOK / BM, NE);
    ffn1_kernel<<<gA, 256, 0, stream>>>(x, w1, b1, w2, b2, counts, lists, Hbuf);

    dim3 gB(DIM / BN, N_TOK / BM, NE);
    ffn2_kernel<<<gB, 256, 0, stream>>>(Hbuf, w3, b3, counts, lists, wts, out);
}

// Round 3
// 841.239 us; speedup vs baseline: 3.4495x; 3.4495x over previous
//
#include <hip/hip_runtime.h>
#include <hip/hip_bf16.h>
#include <math.h>

#define N_TOK 8192
#define DIM   1024
#define HID   2048
#define NE    8

typedef __attribute__((ext_vector_type(8))) short short8;
typedef __attribute__((ext_vector_type(4))) float f32x4;

__device__ __forceinline__ unsigned short f2bf(float f) {
    unsigned int u = __builtin_bit_cast(unsigned int, f);
    unsigned int r = (u + 0x7fffu + ((u >> 16) & 1u)) >> 16;   // RNE
    return (unsigned short)r;
}

__device__ __forceinline__ short8 pack8(float4 a, float4 b) {
    short8 v;
    v[0] = (short)f2bf(a.x); v[1] = (short)f2bf(a.y);
    v[2] = (short)f2bf(a.z); v[3] = (short)f2bf(a.w);
    v[4] = (short)f2bf(b.x); v[5] = (short)f2bf(b.y);
    v[6] = (short)f2bf(b.z); v[7] = (short)f2bf(b.w);
    return v;
}

// ---------------- gating: logits -> softmax -> top2 -> routing lists ----------------
__global__ __launch_bounds__(256) void gate_kernel(
    const float* __restrict__ x, const float* __restrict__ gw, const float* __restrict__ gb,
    float* __restrict__ usage, int* __restrict__ counts,
    int* __restrict__ lists, float* __restrict__ wts)
{
    const int wave_in_block = threadIdx.x >> 6;
    const int lane = threadIdx.x & 63;
    const int tok = blockIdx.x * 4 + wave_in_block;

    __shared__ float su[NE];
    if (threadIdx.x < NE) su[threadIdx.x] = 0.f;
    __syncthreads();

    float acc[NE];
#pragma unroll
    for (int e = 0; e < NE; e++) acc[e] = 0.f;

    const float* xr = x + (size_t)tok * DIM;
    for (int d = lane; d < DIM; d += 64) {
        float xv = xr[d];
        const float4* g4 = (const float4*)(gw + (size_t)d * NE);
        float4 ga = g4[0], gc = g4[1];
        acc[0] = fmaf(xv, ga.x, acc[0]);
        acc[1] = fmaf(xv, ga.y, acc[1]);
        acc[2] = fmaf(xv, ga.z, acc[2]);
        acc[3] = fmaf(xv, ga.w, acc[3]);
        acc[4] = fmaf(xv, gc.x, acc[4]);
        acc[5] = fmaf(xv, gc.y, acc[5]);
        acc[6] = fmaf(xv, gc.z, acc[6]);
        acc[7] = fmaf(xv, gc.w, acc[7]);
    }
#pragma unroll
    for (int e = 0; e < NE; e++) {
#pragma unroll
        for (int off = 32; off > 0; off >>= 1)
            acc[e] += __shfl_xor(acc[e], off);
    }

    if (lane == 0) {
        float lg[NE], p[NE];
        float mx = -1e30f;
#pragma unroll
        for (int e = 0; e < NE; e++) { lg[e] = acc[e] + gb[e]; mx = fmaxf(mx, lg[e]); }
        float s = 0.f;
#pragma unroll
        for (int e = 0; e < NE; e++) { p[e] = __expf(lg[e] - mx); s += p[e]; }
        float inv = 1.f / s;
#pragma unroll
        for (int e = 0; e < NE; e++) p[e] *= inv;

#pragma unroll
        for (int e = 0; e < NE; e++) atomicAdd(&su[e], p[e]);

        int e1 = 0; float v1 = p[0];
#pragma unroll
        for (int e = 1; e < NE; e++) if (p[e] > v1) { v1 = p[e]; e1 = e; }
        int e2 = -1; float v2 = -1e30f;
#pragma unroll
        for (int e = 0; e < NE; e++) if (e != e1 && p[e] > v2) { v2 = p[e]; e2 = e; }

        int pos1 = atomicAdd(&counts[e1], 1);
        lists[e1 * N_TOK + pos1] = tok * 2 + 0;
        wts[e1 * N_TOK + pos1] = v1;
        int pos2 = atomicAdd(&counts[e2], 1);
        lists[e2 * N_TOK + pos2] = tok * 2 + 1;
        wts[e2 * N_TOK + pos2] = v2;
    }
    __syncthreads();
    if (threadIdx.x < NE) atomicAdd(&usage[threadIdx.x], su[threadIdx.x]);
}

__global__ void loss_kernel(const float* __restrict__ usage, float* __restrict__ out_loss)
{
    if (threadIdx.x == 0) {
        float l = 0.f;
        for (int e = 0; e < NE; e++) {
            float u = usage[e] / (float)N_TOK;
            l += u * logf(u + 1e-9f);
        }
        *out_loss = l;
    }
}

// ---------------- W (f32 [R][C]) -> WT (bf16 [C][R]) per expert ----------------
__global__ __launch_bounds__(256) void transpose_bf16_kernel(
    const float* __restrict__ in, unsigned short* __restrict__ out, int R, int C)
{
    __shared__ float Ls[64][65];
    const int e = blockIdx.z;
    const float* in_e = in + (size_t)e * R * C;
    unsigned short* out_e = out + (size_t)e * R * C;
    const int c0 = blockIdx.x * 64, r0 = blockIdx.y * 64;
    const int t = threadIdx.x;
    const int rr = t >> 4, cc = (t & 15) * 4;
#pragma unroll
    for (int it = 0; it < 4; it++) {
        float4 v = *(const float4*)(in_e + (size_t)(r0 + rr + it * 16) * C + c0 + cc);
        Ls[rr + it * 16][cc + 0] = v.x;
        Ls[rr + it * 16][cc + 1] = v.y;
        Ls[rr + it * 16][cc + 2] = v.z;
        Ls[rr + it * 16][cc + 3] = v.w;
    }
    __syncthreads();
#pragma unroll
    for (int it = 0; it < 2; it++) {
        int idx = t + it * 256;
        int a = idx >> 3, b8 = (idx & 7) * 8;
        short8 v;
#pragma unroll
        for (int j = 0; j < 8; j++) v[j] = (short)f2bf(Ls[b8 + j][a]);
        *(short8*)(out_e + (size_t)(c0 + a) * R + r0 + b8) = v;
    }
}

// ---------------- pass A: Xg @ {w1,w2} + bias -> swiglu -> Hbuf (bf16) ----------------
// MFMA 16x16x32 bf16; tile 128x128xBK32; 4 waves, each 64x64 (4x4 frags), dual acc.
__global__ __launch_bounds__(256, 2) void ffn1_mfma_kernel(
    const float* __restrict__ x,
    const unsigned short* __restrict__ W1T, const unsigned short* __restrict__ W2T,
    const float* __restrict__ b1, const float* __restrict__ b2,
    const int* __restrict__ counts, const int* __restrict__ lists,
    unsigned short* __restrict__ Hbuf)
{
    const int e = blockIdx.z;
    const int cnt = counts[e];
    const int m0 = blockIdx.y * 128;
    if (m0 >= cnt) return;
    const int n0 = blockIdx.x * 128;

    __shared__ __align__(16) short As[128][40];   // [m][k], 80B pitch
    __shared__ __align__(16) short B1s[128][40];  // [n][k]
    __shared__ __align__(16) short B2s[128][40];
    __shared__ int rowids[128];

    const int t = threadIdx.x;
    if (t < 128) {
        int idx = m0 + t;
        rowids[t] = (idx < cnt) ? lists[e * N_TOK + idx] : -1;
    }
    __syncthreads();

    const unsigned short* W1p = W1T + (size_t)e * DIM * HID;  // rows n (len DIM)
    const unsigned short* W2p = W2T + (size_t)e * DIM * HID;

    f32x4 acc1[4][4], acc2[4][4];
    const f32x4 fz = {0.f, 0.f, 0.f, 0.f};
#pragma unroll
    for (int i = 0; i < 4; i++)
#pragma unroll
        for (int j = 0; j < 4; j++) { acc1[i][j] = fz; acc2[i][j] = fz; }

    const int lane = t & 63, wv = t >> 6;
    const int wm = (wv >> 1) * 64, wn = (wv & 1) * 64;
    const int fr = lane & 15, kc = lane >> 4;

    const int sr = t >> 1;        // staging row 0..127
    const int sh = t & 1;         // k-half (16 elems)
    const int srid = rowids[sr];
    const short8 z8 = {0, 0, 0, 0, 0, 0, 0, 0};

    for (int k0 = 0; k0 < DIM; k0 += 32) {
        // A: gather x rows, f32 -> bf16
        short8 pa = z8, pb = z8;
        if (srid >= 0) {
            const float* src = x + (size_t)(srid >> 1) * DIM + k0 + sh * 16;
            float4 v0 = ((const float4*)src)[0];
            float4 v1 = ((const float4*)src)[1];
            float4 v2 = ((const float4*)src)[2];
            float4 v3 = ((const float4*)src)[3];
            pa = pack8(v0, v1);
            pb = pack8(v2, v3);
        }
        *(short8*)&As[sr][sh * 16]     = pa;
        *(short8*)&As[sr][sh * 16 + 8] = pb;

        // B: bf16 direct moves
        const unsigned short* s1 = W1p + (size_t)(n0 + sr) * DIM + k0 + sh * 16;
        const unsigned short* s2 = W2p + (size_t)(n0 + sr) * DIM + k0 + sh * 16;
        int4 u0 = ((const int4*)s1)[0], u1 = ((const int4*)s1)[1];
        int4 w0 = ((const int4*)s2)[0], w1v = ((const int4*)s2)[1];
        *(int4*)&B1s[sr][sh * 16]     = u0;
        *(int4*)&B1s[sr][sh * 16 + 8] = u1;
        *(int4*)&B2s[sr][sh * 16]     = w0;
        *(int4*)&B2s[sr][sh * 16 + 8] = w1v;

        __syncthreads();

        short8 af[4];
#pragma unroll
        for (int mi = 0; mi < 4; mi++)
            af[mi] = *(const short8*)&As[wm + mi * 16 + fr][kc * 8];
#pragma unroll
        for (int ni = 0; ni < 4; ni++) {
            short8 bf1 = *(const short8*)&B1s[wn + ni * 16 + fr][kc * 8];
            short8 bf2 = *(const short8*)&B2s[wn + ni * 16 + fr][kc * 8];
#pragma unroll
            for (int mi = 0; mi < 4; mi++) {
                acc1[mi][ni] = __builtin_amdgcn_mfma_f32_16x16x32_bf16(af[mi], bf1, acc1[mi][ni], 0, 0, 0);
                acc2[mi][ni] = __builtin_amdgcn_mfma_f32_16x16x32_bf16(af[mi], bf2, acc2[mi][ni], 0, 0, 0);
            }
        }
        __syncthreads();
    }

    // epilogue: bias + swiglu, store bf16 H rows
#pragma unroll
    for (int ni = 0; ni < 4; ni++) {
        int col = n0 + wn + ni * 16 + fr;
        float bb1 = b1[e * HID + col];
        float bb2 = b2[e * HID + col];
#pragma unroll
        for (int mi = 0; mi < 4; mi++) {
#pragma unroll
            for (int j = 0; j < 4; j++) {
                int rl = wm + mi * 16 + kc * 4 + j;
                int rid = rowids[rl];
                if (rid < 0) continue;
                float v1 = acc1[mi][ni][j] + bb1;
                float v2 = acc2[mi][ni][j] + bb2;
                float h = v1 * (1.f / (1.f + __expf(-v2)));
                Hbuf[(size_t)rid * HID + col] = f2bf(h);
            }
        }
    }
}

// ---------------- pass B: Hg @ w3 + b3, scale, atomicAdd into out ----------------
__global__ __launch_bounds__(256, 2) void ffn2_mfma_kernel(
    const unsigned short* __restrict__ Hbuf,
    const unsigned short* __restrict__ W3T, const float* __restrict__ b3,
    const int* __restrict__ counts, const int* __restrict__ lists, const float* __restrict__ wts,
    float* __restrict__ out)
{
    const int e = blockIdx.z;
    const int cnt = counts[e];
    const int m0 = blockIdx.y * 128;
    if (m0 >= cnt) return;
    const int n0 = blockIdx.x * 128;

    __shared__ __align__(16) short As[128][40];
    __shared__ __align__(16) short B3s[128][40];
    __shared__ int rowids[128];
    __shared__ float rowwt[128];

    const int t = threadIdx.x;
    if (t < 128) {
        int idx = m0 + t;
        if (idx < cnt) { rowids[t] = lists[e * N_TOK + idx]; rowwt[t] = wts[e * N_TOK + idx]; }
        else           { rowids[t] = -1; rowwt[t] = 0.f; }
    }
    __syncthreads();

    const unsigned short* W3p = W3T + (size_t)e * DIM * HID;  // rows n (len HID)

    f32x4 acc[4][4];
    const f32x4 fz = {0.f, 0.f, 0.f, 0.f};
#pragma unroll
    for (int i = 0; i < 4; i++)
#pragma unroll
        for (int j = 0; j < 4; j++) acc[i][j] = fz;

    const int lane = t & 63, wv = t >> 6;
    const int wm = (wv >> 1) * 64, wn = (wv & 1) * 64;
    const int fr = lane & 15, kc = lane >> 4;

    const int sr = t >> 1;
    const int sh = t & 1;
    const int srid = rowids[sr];
    const short8 z8 = {0, 0, 0, 0, 0, 0, 0, 0};

    for (int k0 = 0; k0 < HID; k0 += 32) {
        if (srid >= 0) {
            const unsigned short* src = Hbuf + (size_t)srid * HID + k0 + sh * 16;
            int4 a0 = ((const int4*)src)[0], a1 = ((const int4*)src)[1];
            *(int4*)&As[sr][sh * 16]     = a0;
            *(int4*)&As[sr][sh * 16 + 8] = a1;
        } else {
            *(short8*)&As[sr][sh * 16]     = z8;
            *(short8*)&As[sr][sh * 16 + 8] = z8;
        }
        const unsigned short* s3 = W3p + (size_t)(n0 + sr) * HID + k0 + sh * 16;
        int4 u0 = ((const int4*)s3)[0], u1 = ((const int4*)s3)[1];
        *(int4*)&B3s[sr][sh * 16]     = u0;
        *(int4*)&B3s[sr][sh * 16 + 8] = u1;

        __syncthreads();

        short8 af[4];
#pragma unroll
        for (int mi = 0; mi < 4; mi++)
            af[mi] = *(const short8*)&As[wm + mi * 16 + fr][kc * 8];
#pragma unroll
        for (int ni = 0; ni < 4; ni++) {
            short8 bf3 = *(const short8*)&B3s[wn + ni * 16 + fr][kc * 8];
#pragma unroll
            for (int mi = 0; mi < 4; mi++)
                acc[mi][ni] = __builtin_amdgcn_mfma_f32_16x16x32_bf16(af[mi], bf3, acc[mi][ni], 0, 0, 0);
        }
        __syncthreads();
    }

#pragma unroll
    for (int ni = 0; ni < 4; ni++) {
        int col = n0 + wn + ni * 16 + fr;
        float bb3 = b3[e * DIM + col];
#pragma unroll
        for (int mi = 0; mi < 4; mi++) {
#pragma unroll
            for (int j = 0; j < 4; j++) {
                int rl = wm + mi * 16 + kc * 4 + j;
                int rid = rowids[rl];
                if (rid < 0) continue;
                float v = (acc[mi][ni][j] + bb3) * rowwt[rl];
                atomicAdd(&out[(size_t)(rid >> 1) * DIM + col], v);
            }
        }
    }
}

extern "C" void kernel_launch(void* const* d_in, const int* in_sizes, int n_in,
                              void* d_out, int out_size, void* d_ws, size_t ws_size,
                              hipStream_t stream) {
    (void)in_sizes; (void)n_in; (void)out_size; (void)ws_size;
    const float* x      = (const float*)d_in[0];
    const float* gate_w = (const float*)d_in[1];
    const float* gate_b = (const float*)d_in[2];
    const float* w1     = (const float*)d_in[3];
    const float* b1     = (const float*)d_in[4];
    const float* w2     = (const float*)d_in[5];
    const float* b2     = (const float*)d_in[6];
    const float* w3     = (const float*)d_in[7];
    const float* b3     = (const float*)d_in[8];
    float* out = (float*)d_out;

    char* ws = (char*)d_ws;
    float* usage  = (float*)ws;                                  // 32 B
    int*   counts = (int*)(ws + 32);                             // 32 B
    int*   lists  = (int*)(ws + 64);                             // 256 KB
    float* wts    = (float*)(ws + 64 + (size_t)NE * N_TOK * 4);  // 256 KB
    unsigned short* Hbuf = (unsigned short*)(ws + (1u << 20));                       // 64 MiB
    unsigned short* W1T  = (unsigned short*)(ws + (1u << 20) + (65ull << 20) - (1ull << 20));  // @65 MiB
    // clearer: W1T @ 1MiB + 64MiB, W2T @ +32MiB, W3T reuses W1T after ffn1
    W1T = (unsigned short*)(ws + (65ull << 20));
    unsigned short* W2T = (unsigned short*)(ws + (97ull << 20));
    unsigned short* W3T = W1T;

    hipMemsetAsync(ws, 0, 64, stream);
    hipMemsetAsync(d_out, 0, (size_t)N_TOK * DIM * sizeof(float), stream);

    gate_kernel<<<N_TOK / 4, 256, 0, stream>>>(x, gate_w, gate_b, usage, counts, lists, wts);
    loss_kernel<<<1, 64, 0, stream>>>(usage, out + (size_t)N_TOK * DIM);

    // w1, w2: R=DIM rows, C=HID cols -> WT [HID][DIM]
    dim3 gT1(HID / 64, DIM / 64, NE);
    transpose_bf16_kernel<<<gT1, 256, 0, stream>>>(w1, W1T, DIM, HID);
    transpose_bf16_kernel<<<gT1, 256, 0, stream>>>(w2, W2T, DIM, HID);

    dim3 gA(HID / 128, N_TOK / 128, NE);
    ffn1_mfma_kernel<<<gA, 256, 0, stream>>>(x, W1T, W2T, b1, b2, counts, lists, Hbuf);

    // w3: R=HID rows, C=DIM cols -> W3T [DIM][HID]  (reuses W1T space)
    dim3 gT3(DIM / 64, HID / 64, NE);
    transpose_bf16_kernel<<<gT3, 256, 0, stream>>>(w3, W3T, HID, DIM);

    dim3 gB(DIM / 128, N_TOK / 128, NE);
    ffn2_mfma_kernel<<<gB, 256, 0, stream>>>(Hbuf, W3T, b3, counts, lists, wts, out);
}